// Round 9
// baseline (69.936 us; speedup 1.0000x reference)
//
#include <hip/hip_runtime.h>
#include <stdint.h>

#define NCLS 80
#define TOPK 200
#define CONF_T 0.05f
#define CROPF 300.0f
#define NA 49104
#define NB 8
#define NSEL 256
#define MKEYS 4096
#define APB 64
#define CHUNK (APB * 81)
#define NGRP (NA / 16)          // 3069 16-anchor groups per image (16 | NA)
#define MROW 5                  // mask row stride in u64
#define OUTFLO ((NCLS + 1) * TOPK * 5)   // 81000 floats per image
#define NBLK1 ((NB * NA) / APB)          // 6138 phase1 blocks
#define BPI 192                 // boxmax blocks per image (192*256 = 49152 >= NA)

__device__ __forceinline__ void decode_box(const float4 rg, const float4 an,
                                           float& x1, float& y1, float& x2, float& y2) {
    // anchors: (ymin, xmin, ymax, xmax); reg: (dy, dx, dh, dw)
    float yca = (an.x + an.z) * 0.5f;
    float xca = (an.y + an.w) * 0.5f;
    float ha = an.z - an.x;
    float wa = an.w - an.y;
    float w = expf(rg.w) * wa;
    float h = expf(rg.z) * ha;
    float yc = rg.x * ha + yca;
    float xc = rg.y * wa + xca;
    x1 = fmaxf(xc - w * 0.5f, 0.0f) / CROPF;
    y1 = fmaxf(yc - h * 0.5f, 0.0f) / CROPF;
    x2 = fminf(xc + w * 0.5f, CROPF - 1.0f) / CROPF;
    y2 = fminf(yc + h * 0.5f, CROPF - 1.0f) / CROPF;
}

__device__ __forceinline__ float rlf(float v, int l) {
    return __int_as_float(__builtin_amdgcn_readlane(__float_as_int(v), l));
}

// Phase 1 (r3-proven form): conf -> (scores, cls) + per-16-anchor-group score max.
// NO box decode here (that tripled its runtime in r4-r8). Also stripe-zeros d_out.
__global__ __launch_bounds__(256) void phase1_kernel(
    const float* __restrict__ conf, float* __restrict__ scores,
    unsigned char* __restrict__ cls, float* __restrict__ gms,
    float* __restrict__ outz)
{
    __shared__ float lds[CHUNK];
    const int blk = blockIdx.x, t = threadIdx.x;

    // ---- stripe-zero d_out (2.6MB over 1.57M threads -> <=1 float4 store each)
    {
        const int gid = blk * 256 + t;
        constexpr int TOT4 = NB * OUTFLO / 4;      // 162000 float4s
        if (gid < TOT4)
            reinterpret_cast<float4*>(outz)[gid] = make_float4(0.f, 0.f, 0.f, 0.f);
    }

    const float4* src = reinterpret_cast<const float4*>(conf + (size_t)blk * CHUNK);
    float4* dst = reinterpret_cast<float4*>(lds);
    for (int i = t; i < CHUNK / 4; i += 256) dst[i] = src[i];
    __syncthreads();

    const int la = t >> 2, sub = t & 3;
    const int quad = blk * APB + la;           // global anchor b*NA + a
    const float* crow = lds + la * 81;
    float best = -3.0e38f; int bc = 255;
    for (int c = sub; c <= NCLS; c += 4) {
        if (c == 0) continue;                  // background stripped
        float v = crow[c];
        if (v > best) { best = v; bc = c; }    // strict > : first-index tie-break
    }
    for (int m = 1; m <= 2; m <<= 1) {
        float ov = __shfl_xor(best, m);
        int oc = __shfl_xor(bc, m);
        if (ov > best || (ov == best && oc < bc)) { best = ov; bc = oc; }
    }
    if (sub == 0) {
        scores[quad] = 1.0f / (1.0f + expf(-best));
        cls[quad] = (unsigned char)(bc - 1);
    }
    float wbest = best;                        // group max logit (monotone -> score max)
    #pragma unroll
    for (int m = 1; m < 64; m <<= 1) wbest = fmaxf(wbest, __shfl_xor(wbest, m));
    if ((t & 63) == 0)
        gms[blk * 4 + (t >> 6)] = 1.0f / (1.0f + expf(-wbest));
}

// Boxmax: every lane decodes one anchor (fully coalesced), block-reduce max of
// decoded coords -> blockmax[b*BPI + blkInImg]. 1536 blocks, ~3us.
__global__ __launch_bounds__(256) void boxmax_kernel(
    const float* __restrict__ reg, const float* __restrict__ anch,
    float* __restrict__ blockmax)
{
    __shared__ float wmax[4];
    const int blk = blockIdx.x, t = threadIdx.x;
    const int b = blk / BPI, bi = blk % BPI;
    const int a = bi * 256 + t;
    float m = 0.0f;                            // max coord >= 0 always (ymin >= 0)
    if (a < NA) {
        float4 rg = reinterpret_cast<const float4*>(reg)[(size_t)b * NA + a];
        float4 an = reinterpret_cast<const float4*>(anch)[a];
        float x1, y1, x2, y2; decode_box(rg, an, x1, y1, x2, y2);
        m = fmaxf(fmaxf(x1, y1), fmaxf(x2, y2));
    }
    #pragma unroll
    for (int s = 1; s < 64; s <<= 1) m = fmaxf(m, __shfl_xor(m, s));
    if ((t & 63) == 0) wmax[t >> 6] = m;
    __syncthreads();
    if (t == 0)
        blockmax[blk] = fmaxf(fmaxf(wmax[0], wmax[1]), fmaxf(wmax[2], wmax[3]));
}

// block-wide inclusive SUFFIX scan over 1024 values; result into outarr[t].
__device__ __forceinline__ void suffix_scan_1024(uint32_t v, int t,
                                                 uint32_t* wtot, uint32_t* outarr) {
    uint32_t r = v;
    const int lane = t & 63, w = t >> 6;
    #pragma unroll
    for (int m = 1; m < 64; m <<= 1) {
        uint32_t o = __shfl_down(r, m);
        if (lane + m < 64) r += o;
    }
    if (lane == 0) wtot[w] = r;
    __syncthreads();
    if (t < 16) {
        uint32_t v0 = wtot[t], x = v0;
        #pragma unroll
        for (int m = 1; m < 16; m <<= 1) {
            uint32_t o = __shfl_down(x, m);
            if (t + m < 16) x += o;
        }
        wtot[t] = x - v0;                      // exclusive suffix of wave totals
    }
    __syncthreads();
    outarr[t] = r + wtot[w];
    __syncthreads();
}

// Phase 2: one block/image. Radix-select on 3069 GROUP maxes; gather only
// qualified groups' anchors; readlane rank sort; readlane 256x256 mask build;
// Jacobi-fixpoint exact greedy NMS; popcount output; exact serial fallback.
__global__ __launch_bounds__(1024) void phase2_kernel(
    const float* __restrict__ reg, const float* __restrict__ anch,
    const float* __restrict__ scores, const unsigned char* __restrict__ cls,
    const float* __restrict__ gms, const float* __restrict__ blockmax,
    float* __restrict__ out)
{
    __shared__ uint64_t s_keys[MKEYS];        // 32KB  alias: hist u32[8192]
    __shared__ uint64_t s_skeys[MKEYS];       // 32KB  alias: csum u32[1024]
    __shared__ uint64_t s_mask[256 * MROW];   // 10KB
    __shared__ float4   s_boxo[256];          // 4KB
    __shared__ float    s_areao[256];
    __shared__ float    s_gm[NGRP + 3];       // 12KB group score maxes
    __shared__ uint32_t s_glist[2048];        // 8KB   alias: fhist u32[2048]
    __shared__ float4   s_keptbox[TOPK];      // fallback only
    __shared__ uint64_t s_clsmask[NCLS][4];   // keep-bit mask per class
    __shared__ uint32_t s_ccount[NCLS];
    __shared__ uint32_t s_wtot[16];
    __shared__ uint32_t s_shv[12];
    __shared__ float    s_bmaxarr[16];
    __shared__ float    s_offm;
    __shared__ uint8_t  s_clsl[256];
    __shared__ uint64_t s_K[4], s_newK[4];
    __shared__ uint32_t s_chg;

    uint32_t* hist  = (uint32_t*)s_keys;
    uint32_t* fhist = s_glist;
    uint32_t* csum  = (uint32_t*)s_skeys;

    const int b = blockIdx.x;
    const int t = threadIdx.x;

    // ---- init
    for (int i = t; i < 8192; i += 1024) hist[i] = 0;
    if (t < 12) s_shv[t] = 0;
    __syncthreads();

    // ---- step 1: load group score maxes; coarse hist (bits>>17); box max from blockmax
    {
        const float* gmb = gms + (size_t)b * NGRP;
        for (int i = t; i < NGRP; i += 1024) {
            float v = gmb[i];
            s_gm[i] = v;
            if (v > CONF_T) atomicAdd(&hist[__float_as_uint(v) >> 17], 1u);
        }
        float wm = (t < BPI) ? blockmax[b * BPI + t] : 0.0f;
        #pragma unroll
        for (int m = 1; m < 64; m <<= 1) wm = fmaxf(wm, __shfl_xor(wm, m));
        if ((t & 63) == 0) s_bmaxarr[t >> 6] = wm;
    }
    __syncthreads();

    // ---- coarse crossing via suffix scan over 1024 chunk-sums
    uint32_t v8 = 0;
    #pragma unroll
    for (int k = 0; k < 8; ++k) v8 += hist[t * 8 + k];
    suffix_scan_1024(v8, t, s_wtot, csum);
    {
        uint32_t sIn = csum[t];
        uint32_t sNext = (t == 1023) ? 0u : csum[t + 1];
        if (sIn >= NSEL && sNext < NSEL) { s_shv[0] = (uint32_t)t; s_shv[1] = sNext; s_shv[2] = 1; }
    }
    __syncthreads();
    for (int i = t; i < 2048; i += 1024) fhist[i] = 0;
    if (t == 0) {
        float mx = s_bmaxarr[0];
        #pragma unroll
        for (int k = 1; k < 16; ++k) mx = fmaxf(mx, s_bmaxarr[k]);
        s_offm = mx + 1.0f;                    // jnp.max(boxes) + 1
        if (s_shv[2]) {
            uint32_t chunk = s_shv[0], run2 = s_shv[1]; int cb = -1; uint32_t ab = 0;
            for (int k = 7; k >= 0; --k) {
                uint32_t v = hist[chunk * 8 + k];
                if (cb < 0 && run2 + v >= NSEL) { cb = (int)(chunk * 8 + k); ab = run2; }
                run2 += v;
            }
            s_shv[0] = (uint32_t)cb; s_shv[1] = ab;
        }
    }
    __syncthreads();

    const uint32_t found = s_shv[2], cbin = s_shv[0], above = s_shv[1];
    // ---- fine hist on group maxes in cbin; zero keys (hist now dead)
    for (int i = t; i < MKEYS; i += 1024) s_keys[i] = 0ull;
    if (found) {
        for (int i = t; i < NGRP; i += 1024) {
            float s = s_gm[i];
            if (s > CONF_T) {
                uint32_t bits = __float_as_uint(s);
                if ((bits >> 17) == cbin) atomicAdd(&fhist[(bits >> 6) & 2047u], 1u);
            }
        }
    }
    __syncthreads();
    uint32_t fv = fhist[2 * t] + fhist[2 * t + 1];
    suffix_scan_1024(fv, t, s_wtot, csum);
    if (found) {
        uint32_t sIn = csum[t] + above;
        uint32_t sNext = ((t == 1023) ? 0u : csum[t + 1]) + above;
        if (sIn >= NSEL && sNext < NSEL) { s_shv[5] = (uint32_t)t; s_shv[6] = sNext; }
    }
    __syncthreads();
    if (t == 0) {
        if (found) {
            uint32_t pc = s_shv[5], ab2 = s_shv[6];
            uint32_t v1 = fhist[pc * 2 + 1];
            uint32_t fbin = (ab2 + v1 >= NSEL) ? (pc * 2 + 1) : (pc * 2);
            s_shv[3] = (cbin << 11) | fbin;
        } else s_shv[3] = 0;
    }
    __syncthreads();

    // ---- qualify groups (gmax >= T); fhist dead -> glist
    const uint32_t T = s_shv[3];
    for (int i = t; i < NGRP; i += 1024) {
        float s = s_gm[i];
        if (s > CONF_T && (__float_as_uint(s) >> 6) >= T) {
            uint32_t p = atomicAdd(&s_shv[8], 1u);
            if (p < 2048u) s_glist[p] = (uint32_t)i;
        }
    }
    __syncthreads();
    uint32_t ngl = s_shv[8]; if (ngl > 2048u) ngl = 2048u;

    // ---- gather candidate anchors from qualified groups only
    {
        const float4* sc4 = reinterpret_cast<const float4*>(scores + (size_t)b * NA);
        #define GATH1(s, g) { if ((s) > CONF_T) { uint32_t _b = __float_as_uint(s); \
            if ((_b >> 6) >= T) { uint32_t _p = atomicAdd(&s_shv[4], 1u); \
                if (_p < MKEYS) s_keys[_p] = ((uint64_t)_b << 32) | \
                    (uint64_t)(0xFFFFFFFFu - (uint32_t)(g)); } } }
        for (int idx = t; idx < (int)(ngl * 4); idx += 1024) {
            uint32_t gi = s_glist[idx >> 2];
            int q = idx & 3;
            float4 s4 = sc4[gi * 4 + q];
            uint32_t g0 = gi * 16 + (uint32_t)q * 4;
            GATH1(s4.x, g0)     GATH1(s4.y, g0 + 1)
            GATH1(s4.z, g0 + 2) GATH1(s4.w, g0 + 3)
        }
    }
    __syncthreads();
    uint32_t nGa = s_shv[4]; if (nGa > MKEYS) nGa = MKEYS;
    const int lim = (nGa < 256u) ? (int)nGa : 256;

    // ---- rank sort descending via readlane broadcast (keys unique via ~idx)
    {
        const int lane = t & 63;
        const uint32_t nch = (nGa + 63) >> 6;
        for (int s = 0; s < 4; ++s) {
            int kid = t + s * 1024;
            bool act = kid < (int)nGa;
            if (__ballot(act) == 0ull) continue;
            uint64_t my = act ? s_keys[kid] : ~0ull;
            uint32_t r = 0;
            for (uint32_t ch = 0; ch < nch; ++ch) {
                uint64_t kc = s_keys[ch * 64 + lane];   // pad region zeroed
                uint32_t clo = (uint32_t)kc, chi = (uint32_t)(kc >> 32);
                for (int jj = 0; jj < 64; ++jj) {
                    uint32_t olo = (uint32_t)__builtin_amdgcn_readlane((int)clo, jj);
                    uint32_t ohi = (uint32_t)__builtin_amdgcn_readlane((int)chi, jj);
                    uint64_t ok = ((uint64_t)ohi << 32) | olo;
                    r += (ok > my) ? 1u : 0u;
                }
            }
            if (act) s_skeys[r] = my;
        }
    }
    __syncthreads();

    // ---- prep first 256: offset boxes, areas, classes; init K; zero clsmask
    const float offm = s_offm;
    if (t < 256) {
        if (t < lim) {
            uint64_t key = s_skeys[t];
            uint32_t g = 0xFFFFFFFFu - (uint32_t)key;
            size_t qi = (size_t)b * NA + g;
            int c = (int)cls[qi];
            s_clsl[t] = (uint8_t)c;
            float4 rg = reinterpret_cast<const float4*>(reg)[qi];
            float4 an = reinterpret_cast<const float4*>(anch)[g];
            float x1, y1, x2, y2; decode_box(rg, an, x1, y1, x2, y2);
            float off = (float)c * offm;
            float4 bo = make_float4(x1 + off, y1 + off, x2 + off, y2 + off);
            s_boxo[t] = bo;
            s_areao[t] = (bo.z - bo.x) * (bo.w - bo.y);
        } else {
            s_clsl[t] = 0;
            s_boxo[t] = make_float4(0.f, 0.f, 0.f, 0.f);
            s_areao[t] = 0.f;
        }
    }
    if (t < 4) {
        int lo = t * 64, n = lim - lo;
        s_K[t] = (n >= 64) ? ~0ull : (n > 0 ? ((~0ull) >> (64 - n)) : 0ull);
    }
    if (t < NCLS * 4) ((uint64_t*)s_clsmask)[t] = 0ull;
    __syncthreads();

    // ---- 256x256 suppression mask, register-resident via readlane
    {
        const int wv = t >> 6, lane = t & 63;
        const int rbase = (wv & 3) * 64, c = wv >> 2;
        const int i = rbase + lane;
        float4 bi = s_boxo[i];
        float aI = s_areao[i];
        float4 vj = s_boxo[c * 64 + lane];
        float vA = s_areao[c * 64 + lane];
        uint64_t m = 0ull;
        for (int jj = 0; jj < 64; ++jj) {
            float bx1 = rlf(vj.x, jj), by1 = rlf(vj.y, jj);
            float bx2 = rlf(vj.z, jj), by2 = rlf(vj.w, jj);
            float aJ  = rlf(vA, jj);
            float ix1 = fmaxf(bi.x, bx1), iy1 = fmaxf(bi.y, by1);
            float ix2 = fminf(bi.z, bx2), iy2 = fminf(bi.w, by2);
            float inter = fmaxf(ix2 - ix1, 0.f) * fmaxf(iy2 - iy1, 0.f);
            float uni = aI + aJ - inter;
            if (uni > 0.f && inter + inter > uni) m |= (1ull << jj);
        }
        s_mask[(size_t)i * MROW + c] = m;
    }
    __syncthreads();

    // ---- Jacobi fixpoint greedy NMS (exact: stable iterate == greedy fixpoint)
    {
        const int jw = (t >> 6) & 3, jb = t & 63;
        const uint64_t below = (jb == 0) ? 0ull : ((~0ull) >> (64 - jb));
        const uint64_t* mrow = s_mask + (size_t)(t & 255) * MROW;
        for (int round = 0; round < 300; ++round) {
            bool nb = false;
            if (t < 256) {
                uint64_t dead = 0ull;
                #pragma unroll
                for (int w = 0; w < 4; ++w) {
                    uint64_t mm = mrow[w] & s_K[w];
                    if (w < jw) dead |= mm;
                    else if (w == jw) dead |= (mm & below);
                }
                nb = (dead == 0ull) && (t < lim);
            }
            uint64_t bal = __ballot(nb);
            if (t < 256 && (t & 63) == 0) s_newK[jw] = bal;
            if (t == 0) s_chg = 0;
            __syncthreads();
            if (t < 4 && s_newK[t] != s_K[t]) atomicOr(&s_chg, 1u);
            __syncthreads();
            if (!s_chg) break;
            if (t < 4) s_K[t] = s_newK[t];
            __syncthreads();
        }
    }

    // ---- per-class keep masks + counts + total keeps
    if (t < 256 && ((s_K[(t >> 6) & 3] >> (t & 63)) & 1ull))
        atomicOr(&s_clsmask[s_clsl[t]][(t >> 6) & 3], 1ull << (t & 63));
    __syncthreads();
    if (t < NCLS) {
        uint32_t n = 0;
        #pragma unroll
        for (int w = 0; w < 4; ++w) n += (uint32_t)__popcll(s_clsmask[t][w]);
        s_ccount[t] = n;
    }
    if (t == 0) {
        uint32_t n = 0;
        #pragma unroll
        for (int w = 0; w < 4; ++w) n += (uint32_t)__popcll(s_K[w]);
        s_shv[7] = n;
    }
    __syncthreads();

    // ---- parallel output of first TOPK keeps (order & slot via masked popcounts)
    {
        const int jw = (t >> 6) & 3, jb = t & 63;
        bool kept = (t < 256) && ((s_K[jw] >> jb) & 1ull);
        if (kept) {
            const uint64_t below = (jb == 0) ? 0ull : ((~0ull) >> (64 - jb));
            uint32_t ord = (uint32_t)__popcll(s_K[jw] & below);
            for (int w = 0; w < jw; ++w) ord += (uint32_t)__popcll(s_K[w]);
            if (ord < TOPK) {
                int c = (int)s_clsl[t];
                const uint64_t* cm = s_clsmask[c];
                uint32_t slot = (uint32_t)__popcll(cm[jw] & below);
                for (int w = 0; w < jw; ++w) slot += (uint32_t)__popcll(cm[w]);
                uint64_t key = s_skeys[t];
                uint32_t g = 0xFFFFFFFFu - (uint32_t)key;
                float scv = __uint_as_float((uint32_t)(key >> 32));
                size_t qi = (size_t)b * NA + g;
                float4 rg = reinterpret_cast<const float4*>(reg)[qi];
                float4 an = reinterpret_cast<const float4*>(anch)[g];
                float x1, y1, x2, y2; decode_box(rg, an, x1, y1, x2, y2);
                float* o = out + (((size_t)b * (NCLS + 1) + (size_t)(c + 1)) * TOPK + slot) * 5;
                o[0] = scv; o[1] = x1; o[2] = y1; o[3] = x2; o[4] = y2;
                s_keptbox[ord] = s_boxo[t];    // for fallback
            }
        }
    }
    __syncthreads();

    // ---- serial fallback past lim (exactness insurance; ~never taken)
    if (t == 0) {
        uint32_t nk = s_shv[7];
        if (nk < TOPK && nGa > (uint32_t)lim) {
            for (uint32_t ci = (uint32_t)lim; ci < nGa && nk < TOPK; ++ci) {
                uint64_t key = s_skeys[ci];
                uint32_t g = 0xFFFFFFFFu - (uint32_t)key;
                size_t qi = (size_t)b * NA + g;
                int c = (int)cls[qi];
                float4 rg = reinterpret_cast<const float4*>(reg)[qi];
                float4 an = reinterpret_cast<const float4*>(anch)[g];
                float x1, y1, x2, y2; decode_box(rg, an, x1, y1, x2, y2);
                float off = (float)c * offm;
                float4 bo = make_float4(x1 + off, y1 + off, x2 + off, y2 + off);
                float aB2 = (bo.z - bo.x) * (bo.w - bo.y);
                bool sup = false;
                for (uint32_t k2 = 0; k2 < nk && !sup; ++k2) {
                    float4 kb = s_keptbox[k2];
                    float aK = (kb.z - kb.x) * (kb.w - kb.y);
                    float ix1 = fmaxf(bo.x, kb.x), iy1 = fmaxf(bo.y, kb.y);
                    float ix2 = fminf(bo.z, kb.z), iy2 = fminf(bo.w, kb.w);
                    float inter = fmaxf(ix2 - ix1, 0.f) * fmaxf(iy2 - iy1, 0.f);
                    float uni = aB2 + aK - inter;
                    sup = (uni > 0.f && inter + inter > uni);
                }
                if (!sup) {
                    uint32_t slot = s_ccount[c]; s_ccount[c] = slot + 1;
                    float scv = __uint_as_float((uint32_t)(key >> 32));
                    float* o = out + (((size_t)b * (NCLS + 1) + (size_t)(c + 1)) * TOPK + slot) * 5;
                    o[0] = scv; o[1] = x1; o[2] = y1; o[3] = x2; o[4] = y2;
                    s_keptbox[nk] = bo;
                    ++nk;
                }
            }
        }
    }
}

extern "C" void kernel_launch(void* const* d_in, const int* in_sizes, int n_in,
                              void* d_out, int out_size, void* d_ws, size_t ws_size,
                              hipStream_t stream)
{
    const float* conf = (const float*)d_in[0];   // [B, A, 81] f32
    const float* reg  = (const float*)d_in[1];   // [B, A, 4]  f32
    const float* anch = (const float*)d_in[2];   // [A, 4]     f32
    float* out = (float*)d_out;                  // [B, 81, 200, 5] f32

    char* ws = (char*)d_ws;
    float* scores = (float*)ws;                                        // NB*NA f32
    float* gms = (float*)(ws + (size_t)NB * NA * 4);                   // NB*NGRP f32
    float* blockmax = (float*)(ws + (size_t)NB * NA * 4
                                  + (size_t)NB * NGRP * 4);            // NB*BPI f32
    unsigned char* cls = (unsigned char*)(ws + (size_t)NB * NA * 4
                                             + (size_t)NB * NGRP * 4
                                             + (size_t)NB * BPI * 4);  // NB*NA u8

    // d_out zeroing striped inside phase1; box-max in its own full-width kernel
    phase1_kernel<<<NBLK1, 256, 0, stream>>>(conf, scores, cls, gms, out);
    boxmax_kernel<<<NB * BPI, 256, 0, stream>>>(reg, anch, blockmax);
    phase2_kernel<<<NB, 1024, 0, stream>>>(reg, anch, scores, cls, gms, blockmax, out);
}

// Round 10
// 63.436 us; speedup vs baseline: 1.1025x; 1.1025x over previous
//
#include <hip/hip_runtime.h>
#include <stdint.h>

#define NCLS 80
#define TOPK 200
#define CONF_T 0.05f
#define CROPF 300.0f
#define NA 49104
#define NB 8
#define NSEL 256
#define MKEYS 4096
#define APB 64
#define CHUNK (APB * 81)
#define NGRP (NA / 16)          // 3069 16-anchor groups per image (16 | NA)
#define MROW 5                  // mask row stride in u64
#define OUTFLO ((NCLS + 1) * TOPK * 5)   // 81000 floats per image
#define NBLK1 ((NB * NA) / APB)          // 6138 phase1 blocks
#define BASE13 125542u          // 0x3D4CCCCD >> 13  (CONF_T bit floor)
#define NBINS 4512              // covers (0.05, 1.0] in >>13 space (4507 used)

__device__ __forceinline__ void decode_box(const float4 rg, const float4 an,
                                           float& x1, float& y1, float& x2, float& y2) {
    // anchors: (ymin, xmin, ymax, xmax); reg: (dy, dx, dh, dw)
    float yca = (an.x + an.z) * 0.5f;
    float xca = (an.y + an.w) * 0.5f;
    float ha = an.z - an.x;
    float wa = an.w - an.y;
    float w = expf(rg.w) * wa;
    float h = expf(rg.z) * ha;
    float yc = rg.x * ha + yca;
    float xc = rg.y * wa + xca;
    x1 = fmaxf(xc - w * 0.5f, 0.0f) / CROPF;
    y1 = fmaxf(yc - h * 0.5f, 0.0f) / CROPF;
    x2 = fminf(xc + w * 0.5f, CROPF - 1.0f) / CROPF;
    y2 = fminf(yc + h * 0.5f, CROPF - 1.0f) / CROPF;
}

__device__ __forceinline__ float rlf(float v, int l) {
    return __int_as_float(__builtin_amdgcn_readlane(__float_as_int(v), l));
}

// Phase 1 (r8-validated): conf -> (scores, cls); per-16-anchor-group
// float2{max score, max box coord}; stripe-zeros d_out.
__global__ __launch_bounds__(256) void phase1_kernel(
    const float* __restrict__ conf, const float* __restrict__ reg,
    const float* __restrict__ anch, float* __restrict__ scores,
    unsigned char* __restrict__ cls, float2* __restrict__ gm2,
    float* __restrict__ outz)
{
    __shared__ float lds[CHUNK];
    const int blk = blockIdx.x, t = threadIdx.x;

    // ---- stripe-zero d_out (2.6MB over 1.57M threads -> <=1 float4 store each)
    {
        const int gid = blk * 256 + t;
        constexpr int TOT4 = NB * OUTFLO / 4;      // 162000 float4s
        if (gid < TOT4)
            reinterpret_cast<float4*>(outz)[gid] = make_float4(0.f, 0.f, 0.f, 0.f);
    }

    const float4* src = reinterpret_cast<const float4*>(conf + (size_t)blk * CHUNK);
    float4* dst = reinterpret_cast<float4*>(lds);
    for (int i = t; i < CHUNK / 4; i += 256) dst[i] = src[i];
    __syncthreads();

    const int la = t >> 2, sub = t & 3;
    const int quad = blk * APB + la;           // global anchor b*NA + a
    const float* crow = lds + la * 81;
    float best = -3.0e38f; int bc = 255;
    #pragma unroll
    for (int k = 0; k < 20; ++k) {             // lane sub: classes 1+sub, +4 each
        int c = 1 + sub + 4 * k;
        float v = crow[c];
        if (v > best) { best = v; bc = c; }    // strict > : first-index tie-break
    }
    for (int m = 1; m <= 2; m <<= 1) {
        float ov = __shfl_xor(best, m);
        int oc = __shfl_xor(bc, m);
        if (ov > best || (ov == best && oc < bc)) { best = ov; bc = oc; }
    }
    float bmaxl = 0.0f;                        // decoded coords: y1 >= 0, safe identity
    if (sub == 0) {
        scores[quad] = 1.0f / (1.0f + expf(-best));
        cls[quad] = (unsigned char)(bc - 1);
        int a = quad % NA;
        float4 rg = reinterpret_cast<const float4*>(reg)[quad];
        float4 an = reinterpret_cast<const float4*>(anch)[a];
        float x1, y1, x2, y2; decode_box(rg, an, x1, y1, x2, y2);
        bmaxl = fmaxf(fmaxf(x1, y1), fmaxf(x2, y2));
    }
    float wbest = best;                        // group max logit (monotone -> score max)
    #pragma unroll
    for (int m = 1; m < 64; m <<= 1) {
        wbest = fmaxf(wbest, __shfl_xor(wbest, m));
        bmaxl = fmaxf(bmaxl, __shfl_xor(bmaxl, m));
    }
    if ((t & 63) == 0)
        gm2[blk * 4 + (t >> 6)] = make_float2(1.0f / (1.0f + expf(-wbest)), bmaxl);
}

// block-wide inclusive SUFFIX scan over 1024 values; result into outarr[t].
__device__ __forceinline__ void suffix_scan_1024(uint32_t v, int t,
                                                 uint32_t* wtot, uint32_t* outarr) {
    uint32_t r = v;
    const int lane = t & 63, w = t >> 6;
    #pragma unroll
    for (int m = 1; m < 64; m <<= 1) {
        uint32_t o = __shfl_down(r, m);
        if (lane + m < 64) r += o;
    }
    if (lane == 0) wtot[w] = r;
    __syncthreads();
    if (t < 16) {
        uint32_t v0 = wtot[t], x = v0;
        #pragma unroll
        for (int m = 1; m < 16; m <<= 1) {
            uint32_t o = __shfl_down(x, m);
            if (t + m < 16) x += o;
        }
        wtot[t] = x - v0;                      // exclusive suffix of wave totals
    }
    __syncthreads();
    outarr[t] = r + wtot[w];
    __syncthreads();
}

// Phase 2: one block/image. ONE-level >>13 histogram select on group maxes
// (4507 live bins; threshold at bin floor is exact-by-containment); gather from
// qualified groups; readlane rank sort (guarded reads, no zero pass); readlane
// 256x256 mask; Jacobi-fixpoint exact greedy NMS; popcount output; fallback.
__global__ __launch_bounds__(1024) void phase2_kernel(
    const float* __restrict__ reg, const float* __restrict__ anch,
    const float* __restrict__ scores, const unsigned char* __restrict__ cls,
    const float2* __restrict__ gm2, float* __restrict__ out)
{
    __shared__ uint64_t s_keys[MKEYS];        // 32KB  alias: hist u32[NBINS]
    __shared__ uint64_t s_skeys[MKEYS];       // 32KB  alias: csum u32[1024]
    __shared__ uint64_t s_mask[256 * MROW];   // 10KB
    __shared__ float4   s_boxo[256];          // 4KB
    __shared__ float    s_areao[256];
    __shared__ float    s_gm[NGRP + 3];       // 12KB group score maxes
    __shared__ uint32_t s_glist[2048];        // 8KB
    __shared__ float4   s_keptbox[TOPK];      // fallback only
    __shared__ uint64_t s_clsmask[NCLS][4];   // keep-bit mask per class
    __shared__ uint32_t s_ccount[NCLS];
    __shared__ uint32_t s_wtot[16];
    __shared__ uint32_t s_shv[12];
    __shared__ float    s_bmaxarr[16];
    __shared__ float    s_offm;
    __shared__ uint8_t  s_clsl[256];
    __shared__ uint64_t s_K[4], s_newK[4];
    __shared__ uint32_t s_chg;

    uint32_t* hist = (uint32_t*)s_keys;
    uint32_t* csum = (uint32_t*)s_skeys;

    const int b = blockIdx.x;
    const int t = threadIdx.x;

    // ---- init: zero hist + control
    for (int i = t; i < NBINS; i += 1024) hist[i] = 0;
    if (t < 12) s_shv[t] = 0;
    __syncthreads();

    // ---- load group maxes; >>13 histogram; box max
    {
        const float2* gmb = gm2 + (size_t)b * NGRP;
        float wm = 0.0f;
        for (int i = t; i < NGRP; i += 1024) {
            float2 v = gmb[i];
            s_gm[i] = v.x;
            wm = fmaxf(wm, v.y);
            if (v.x > CONF_T) {
                int ib = (int)((__float_as_uint(v.x) >> 13) - BASE13);
                ib = max(0, min(NBINS - 1, ib));
                atomicAdd(&hist[ib], 1u);
            }
        }
        #pragma unroll
        for (int m = 1; m < 64; m <<= 1) wm = fmaxf(wm, __shfl_xor(wm, m));
        if ((t & 63) == 0) s_bmaxarr[t >> 6] = wm;
    }
    __syncthreads();

    // ---- crossing via suffix scan over 1024 chunk-sums (8 bins/chunk; 564 used)
    uint32_t v8 = 0;
    if (t * 8 < NBINS) {
        #pragma unroll
        for (int k = 0; k < 8; ++k) v8 += hist[t * 8 + k];
    }
    suffix_scan_1024(v8, t, s_wtot, csum);
    {
        uint32_t sIn = csum[t];
        uint32_t sNext = (t == 1023) ? 0u : csum[t + 1];
        if (sIn >= NSEL && sNext < NSEL) { s_shv[0] = (uint32_t)t; s_shv[1] = sNext; s_shv[2] = 1; }
    }
    __syncthreads();
    if (t == 0) {
        float mx = s_bmaxarr[0];
        #pragma unroll
        for (int k = 1; k < 16; ++k) mx = fmaxf(mx, s_bmaxarr[k]);
        s_offm = mx + 1.0f;                    // jnp.max(boxes) + 1
        if (s_shv[2]) {
            uint32_t chunk = s_shv[0], run2 = s_shv[1]; int cb = -1;
            for (int k = 7; k >= 0; --k) {
                uint32_t v = hist[chunk * 8 + k];
                if (cb < 0 && run2 + v >= NSEL) cb = (int)(chunk * 8 + k);
                run2 += v;
            }
            s_shv[3] = BASE13 + (uint32_t)cb;  // threshold in >>13 space
        } else s_shv[3] = 0;
    }
    __syncthreads();

    // ---- qualify groups ((gmax bits>>13) >= T13)
    const uint32_t T13 = s_shv[3];
    for (int i = t; i < NGRP; i += 1024) {
        float s = s_gm[i];
        if (s > CONF_T && (__float_as_uint(s) >> 13) >= T13) {
            uint32_t p = atomicAdd(&s_shv[8], 1u);
            if (p < 2048u) s_glist[p] = (uint32_t)i;
        }
    }
    __syncthreads();
    uint32_t ngl = s_shv[8]; if (ngl > 2048u) ngl = 2048u;

    // ---- gather candidate anchors from qualified groups only (hist dead)
    {
        const float4* sc4 = reinterpret_cast<const float4*>(scores + (size_t)b * NA);
        #define GATH1(s, g) { if ((s) > CONF_T) { uint32_t _b = __float_as_uint(s); \
            if ((_b >> 13) >= T13) { uint32_t _p = atomicAdd(&s_shv[4], 1u); \
                if (_p < MKEYS) s_keys[_p] = ((uint64_t)_b << 32) | \
                    (uint64_t)(0xFFFFFFFFu - (uint32_t)(g)); } } }
        for (int idx = t; idx < (int)(ngl * 4); idx += 1024) {
            uint32_t gi = s_glist[idx >> 2];
            int q = idx & 3;
            float4 s4 = sc4[gi * 4 + q];
            uint32_t g0 = gi * 16 + (uint32_t)q * 4;
            GATH1(s4.x, g0)     GATH1(s4.y, g0 + 1)
            GATH1(s4.z, g0 + 2) GATH1(s4.w, g0 + 3)
        }
    }
    __syncthreads();
    uint32_t nGa = s_shv[4]; if (nGa > MKEYS) nGa = MKEYS;
    const int lim = (nGa < 256u) ? (int)nGa : 256;

    // ---- rank sort descending via readlane broadcast (guarded reads, no zeroing)
    {
        const int lane = t & 63;
        const uint32_t nch = (nGa + 63) >> 6;
        for (int s = 0; s < 4; ++s) {
            int kid = t + s * 1024;
            bool act = kid < (int)nGa;
            if (__ballot(act) == 0ull) continue;
            uint64_t my = act ? s_keys[kid] : ~0ull;
            uint32_t r = 0;
            for (uint32_t ch = 0; ch < nch; ++ch) {
                uint32_t src = ch * 64 + (uint32_t)lane;
                uint64_t kc = (src < nGa) ? s_keys[src] : 0ull;
                uint32_t clo = (uint32_t)kc, chi = (uint32_t)(kc >> 32);
                for (int jj = 0; jj < 64; ++jj) {
                    uint32_t olo = (uint32_t)__builtin_amdgcn_readlane((int)clo, jj);
                    uint32_t ohi = (uint32_t)__builtin_amdgcn_readlane((int)chi, jj);
                    uint64_t ok = ((uint64_t)ohi << 32) | olo;
                    r += (ok > my) ? 1u : 0u;
                }
            }
            if (act) s_skeys[r] = my;
        }
    }
    __syncthreads();

    // ---- prep first 256: offset boxes, areas, classes; init K; zero clsmask
    const float offm = s_offm;
    if (t < 256) {
        if (t < lim) {
            uint64_t key = s_skeys[t];
            uint32_t g = 0xFFFFFFFFu - (uint32_t)key;
            size_t qi = (size_t)b * NA + g;
            int c = (int)cls[qi];
            s_clsl[t] = (uint8_t)c;
            float4 rg = reinterpret_cast<const float4*>(reg)[qi];
            float4 an = reinterpret_cast<const float4*>(anch)[g];
            float x1, y1, x2, y2; decode_box(rg, an, x1, y1, x2, y2);
            float off = (float)c * offm;
            float4 bo = make_float4(x1 + off, y1 + off, x2 + off, y2 + off);
            s_boxo[t] = bo;
            s_areao[t] = (bo.z - bo.x) * (bo.w - bo.y);
        } else {
            s_clsl[t] = 0;
            s_boxo[t] = make_float4(0.f, 0.f, 0.f, 0.f);
            s_areao[t] = 0.f;
        }
    }
    if (t < 4) {
        int lo = t * 64, n = lim - lo;
        s_K[t] = (n >= 64) ? ~0ull : (n > 0 ? ((~0ull) >> (64 - n)) : 0ull);
    }
    if (t < NCLS * 4) ((uint64_t*)s_clsmask)[t] = 0ull;
    __syncthreads();

    // ---- 256x256 suppression mask, register-resident via readlane
    {
        const int wv = t >> 6, lane = t & 63;
        const int rbase = (wv & 3) * 64, c = wv >> 2;
        const int i = rbase + lane;
        float4 bi = s_boxo[i];
        float aI = s_areao[i];
        float4 vj = s_boxo[c * 64 + lane];
        float vA = s_areao[c * 64 + lane];
        uint64_t m = 0ull;
        for (int jj = 0; jj < 64; ++jj) {
            float bx1 = rlf(vj.x, jj), by1 = rlf(vj.y, jj);
            float bx2 = rlf(vj.z, jj), by2 = rlf(vj.w, jj);
            float aJ  = rlf(vA, jj);
            float ix1 = fmaxf(bi.x, bx1), iy1 = fmaxf(bi.y, by1);
            float ix2 = fminf(bi.z, bx2), iy2 = fminf(bi.w, by2);
            float inter = fmaxf(ix2 - ix1, 0.f) * fmaxf(iy2 - iy1, 0.f);
            float uni = aI + aJ - inter;
            if (uni > 0.f && inter + inter > uni) m |= (1ull << jj);
        }
        s_mask[(size_t)i * MROW + c] = m;
    }
    __syncthreads();

    // ---- Jacobi fixpoint greedy NMS (exact: stable iterate == greedy fixpoint)
    {
        const int jw = (t >> 6) & 3, jb = t & 63;
        const uint64_t below = (jb == 0) ? 0ull : ((~0ull) >> (64 - jb));
        const uint64_t* mrow = s_mask + (size_t)(t & 255) * MROW;
        for (int round = 0; round < 300; ++round) {
            bool nb = false;
            if (t < 256) {
                uint64_t dead = 0ull;
                #pragma unroll
                for (int w = 0; w < 4; ++w) {
                    uint64_t mm = mrow[w] & s_K[w];
                    if (w < jw) dead |= mm;
                    else if (w == jw) dead |= (mm & below);
                }
                nb = (dead == 0ull) && (t < lim);
            }
            uint64_t bal = __ballot(nb);
            if (t < 256 && (t & 63) == 0) s_newK[jw] = bal;
            if (t == 0) s_chg = 0;
            __syncthreads();
            if (t < 4 && s_newK[t] != s_K[t]) atomicOr(&s_chg, 1u);
            __syncthreads();
            if (!s_chg) break;
            if (t < 4) s_K[t] = s_newK[t];
            __syncthreads();
        }
    }

    // ---- per-class keep masks + counts + total keeps
    if (t < 256 && ((s_K[(t >> 6) & 3] >> (t & 63)) & 1ull))
        atomicOr(&s_clsmask[s_clsl[t]][(t >> 6) & 3], 1ull << (t & 63));
    __syncthreads();
    if (t < NCLS) {
        uint32_t n = 0;
        #pragma unroll
        for (int w = 0; w < 4; ++w) n += (uint32_t)__popcll(s_clsmask[t][w]);
        s_ccount[t] = n;
    }
    if (t == 0) {
        uint32_t n = 0;
        #pragma unroll
        for (int w = 0; w < 4; ++w) n += (uint32_t)__popcll(s_K[w]);
        s_shv[7] = n;
    }
    __syncthreads();

    // ---- parallel output of first TOPK keeps (order & slot via masked popcounts)
    {
        const int jw = (t >> 6) & 3, jb = t & 63;
        bool kept = (t < 256) && ((s_K[jw] >> jb) & 1ull);
        if (kept) {
            const uint64_t below = (jb == 0) ? 0ull : ((~0ull) >> (64 - jb));
            uint32_t ord = (uint32_t)__popcll(s_K[jw] & below);
            for (int w = 0; w < jw; ++w) ord += (uint32_t)__popcll(s_K[w]);
            if (ord < TOPK) {
                int c = (int)s_clsl[t];
                const uint64_t* cm = s_clsmask[c];
                uint32_t slot = (uint32_t)__popcll(cm[jw] & below);
                for (int w = 0; w < jw; ++w) slot += (uint32_t)__popcll(cm[w]);
                uint64_t key = s_skeys[t];
                uint32_t g = 0xFFFFFFFFu - (uint32_t)key;
                float scv = __uint_as_float((uint32_t)(key >> 32));
                size_t qi = (size_t)b * NA + g;
                float4 rg = reinterpret_cast<const float4*>(reg)[qi];
                float4 an = reinterpret_cast<const float4*>(anch)[g];
                float x1, y1, x2, y2; decode_box(rg, an, x1, y1, x2, y2);
                float* o = out + (((size_t)b * (NCLS + 1) + (size_t)(c + 1)) * TOPK + slot) * 5;
                o[0] = scv; o[1] = x1; o[2] = y1; o[3] = x2; o[4] = y2;
                s_keptbox[ord] = s_boxo[t];    // for fallback
            }
        }
    }
    __syncthreads();

    // ---- serial fallback past lim (exactness insurance; ~never taken)
    if (t == 0) {
        uint32_t nk = s_shv[7];
        if (nk < TOPK && nGa > (uint32_t)lim) {
            for (uint32_t ci = (uint32_t)lim; ci < nGa && nk < TOPK; ++ci) {
                uint64_t key = s_skeys[ci];
                uint32_t g = 0xFFFFFFFFu - (uint32_t)key;
                size_t qi = (size_t)b * NA + g;
                int c = (int)cls[qi];
                float4 rg = reinterpret_cast<const float4*>(reg)[qi];
                float4 an = reinterpret_cast<const float4*>(anch)[g];
                float x1, y1, x2, y2; decode_box(rg, an, x1, y1, x2, y2);
                float off = (float)c * offm;
                float4 bo = make_float4(x1 + off, y1 + off, x2 + off, y2 + off);
                float aB2 = (bo.z - bo.x) * (bo.w - bo.y);
                bool sup = false;
                for (uint32_t k2 = 0; k2 < nk && !sup; ++k2) {
                    float4 kb = s_keptbox[k2];
                    float aK = (kb.z - kb.x) * (kb.w - kb.y);
                    float ix1 = fmaxf(bo.x, kb.x), iy1 = fmaxf(bo.y, kb.y);
                    float ix2 = fminf(bo.z, kb.z), iy2 = fminf(bo.w, kb.w);
                    float inter = fmaxf(ix2 - ix1, 0.f) * fmaxf(iy2 - iy1, 0.f);
                    float uni = aB2 + aK - inter;
                    sup = (uni > 0.f && inter + inter > uni);
                }
                if (!sup) {
                    uint32_t slot = s_ccount[c]; s_ccount[c] = slot + 1;
                    float scv = __uint_as_float((uint32_t)(key >> 32));
                    float* o = out + (((size_t)b * (NCLS + 1) + (size_t)(c + 1)) * TOPK + slot) * 5;
                    o[0] = scv; o[1] = x1; o[2] = y1; o[3] = x2; o[4] = y2;
                    s_keptbox[nk] = bo;
                    ++nk;
                }
            }
        }
    }
}

extern "C" void kernel_launch(void* const* d_in, const int* in_sizes, int n_in,
                              void* d_out, int out_size, void* d_ws, size_t ws_size,
                              hipStream_t stream)
{
    const float* conf = (const float*)d_in[0];   // [B, A, 81] f32
    const float* reg  = (const float*)d_in[1];   // [B, A, 4]  f32
    const float* anch = (const float*)d_in[2];   // [A, 4]     f32
    float* out = (float*)d_out;                  // [B, 81, 200, 5] f32

    char* ws = (char*)d_ws;
    float* scores = (float*)ws;                                       // NB*NA f32
    float2* gm2 = (float2*)(ws + (size_t)NB * NA * 4);                // NB*NGRP float2
    unsigned char* cls = (unsigned char*)(ws + (size_t)NB * NA * 4
                                             + (size_t)NB * NGRP * 8); // NB*NA u8

    // d_out zeroing striped inside phase1 (full-GPU, overlapped with conf stream)
    phase1_kernel<<<NBLK1, 256, 0, stream>>>(conf, reg, anch, scores, cls, gm2, out);
    phase2_kernel<<<NB, 1024, 0, stream>>>(reg, anch, scores, cls, gm2, out);
}